// Round 4
// baseline (25.288 us; speedup 1.0000x reference)
//
#include <hip/hip_runtime.h>

#define B_  32
#define T_  256
#define D_  384
#define ML_ 2048
#define ROWS_PER_BLK 64
#define CHUNKS (ML_ / ROWS_PER_BLK)   // 32 chunks per batch

typedef float f4 __attribute__((ext_vector_type(4)));   // native vec: OK for nontemporal builtins

// Fused length-regulator: each block recomputes the per-batch cumsum with a
// register shuffle scan (dur is 32 KB -> L2-resident), binary-searches token
// indices for its 64 output rows, then streams the gathered rows out with
// nontemporal stores (keep L2 for the reused x rows).
__global__ __launch_bounds__(256) void lr_fused_kernel(
    const f4* __restrict__ x4,
    const int* __restrict__ dur,
    const int* __restrict__ max_len_p,
    f4*        __restrict__ out4,
    float*     __restrict__ mel_out)
{
    const int blk   = blockIdx.x;
    const int b     = blk >> 5;                 // / CHUNKS(32)
    const int chunk = blk & (CHUNKS - 1);
    const int tid   = threadIdx.x;
    const int lane  = tid & 63;
    const int wid   = tid >> 6;                 // 4 waves

    __shared__ int cs[T_];
    __shared__ int wtot[4];
    __shared__ int ridx[ROWS_PER_BLK];

    // --- inclusive scan of dur[b,:] : wave shfl scan + cross-wave fixup ---
    int v = dur[b * T_ + tid];
    #pragma unroll
    for (int d = 1; d < 64; d <<= 1) {
        int n = __shfl_up(v, d);
        if (lane >= d) v += n;
    }
    if (lane == 63) wtot[wid] = v;
    __syncthreads();
    int off = 0;
    #pragma unroll
    for (int w = 0; w < 3; ++w) if (w < wid) off += wtot[w];
    cs[tid] = v + off;
    __syncthreads();

    const int total = cs[T_ - 1];
    const int mel   = min(total, max_len_p[0]);
    if (chunk == 0 && tid == 0) mel_out[b] = (float)mel;

    // --- threads 0..63: searchsorted(csum, pos, 'right') for this chunk ---
    if (tid < ROWS_PER_BLK) {
        const int pos = chunk * ROWS_PER_BLK + tid;
        int r = -1;
        if (pos < mel) {
            int lo = 0, hi = T_;                // first t with cs[t] > pos
            #pragma unroll
            for (int s = 0; s < 8; ++s) {
                int mid = (lo + hi) >> 1;
                if (cs[mid] <= pos) lo = mid + 1; else hi = mid;
            }
            r = min(lo, T_ - 1);
        }
        ridx[tid] = r;
    }
    __syncthreads();

    // --- gather + streaming write: 64 rows x 96 float4, 24 per thread ---
    const int rowsz = D_ / 4;                                   // 96
    const f4* xb = x4 + (size_t)b * T_ * rowsz;
    f4* ob = out4 + ((size_t)b * ML_ + (size_t)chunk * ROWS_PER_BLK) * rowsz;
    const int N = ROWS_PER_BLK * rowsz;                         // 6144

    #pragma unroll 4
    for (int i = tid; i < N; i += 256) {
        const int rl   = i / rowsz;             // magic-mul div (rowsz const)
        const int ln   = i - rl * rowsz;
        const int idx  = ridx[rl];
        f4 w;
        if (idx >= 0) w = xb[idx * rowsz + ln];
        else          w = (f4){0.f, 0.f, 0.f, 0.f};
        __builtin_nontemporal_store(w, &ob[i]);
    }
}

extern "C" void kernel_launch(void* const* d_in, const int* in_sizes, int n_in,
                              void* d_out, int out_size, void* d_ws, size_t ws_size,
                              hipStream_t stream) {
    const float* x       = (const float*)d_in[0];
    const int*   dur     = (const int*)d_in[1];
    const int*   max_len = (const int*)d_in[2];
    float*       out     = (float*)d_out;
    float*       mel_out = out + (size_t)B_ * ML_ * D_;         // tail: B_ floats

    lr_fused_kernel<<<B_ * CHUNKS, 256, 0, stream>>>(
        (const f4*)x, dur, max_len, (f4*)out, mel_out);
}

// Round 5
// 24.287 us; speedup vs baseline: 1.0412x; 1.0412x over previous
//
#include <hip/hip_runtime.h>

#define B_  32
#define T_  256
#define D_  384
#define ML_ 2048
#define ROWS_PER_BLK 64
#define CHUNKS (ML_ / ROWS_PER_BLK)   // 32 chunks per batch

typedef float f4 __attribute__((ext_vector_type(4)));

// Fused length-regulator: per-block register shuffle-scan of dur (32 KB total,
// L2-resident), binary search for the 64 rows this block owns, then coalesced
// gather->store with deep unroll for load-latency hiding.
__global__ __launch_bounds__(256) void lr_fused_kernel(
    const f4* __restrict__ x4,
    const int* __restrict__ dur,
    const int* __restrict__ max_len_p,
    f4*        __restrict__ out4,
    float*     __restrict__ mel_out)
{
    const int blk   = blockIdx.x;
    const int b     = blk >> 5;                 // / CHUNKS(32)
    const int chunk = blk & (CHUNKS - 1);
    const int tid   = threadIdx.x;
    const int lane  = tid & 63;
    const int wid   = tid >> 6;                 // 4 waves

    __shared__ int cs[T_];
    __shared__ int wtot[4];
    __shared__ int ridx[ROWS_PER_BLK];

    // --- inclusive scan of dur[b,:] : wave shfl scan + cross-wave fixup ---
    int v = dur[b * T_ + tid];
    #pragma unroll
    for (int d = 1; d < 64; d <<= 1) {
        int n = __shfl_up(v, d);
        if (lane >= d) v += n;
    }
    if (lane == 63) wtot[wid] = v;
    __syncthreads();
    int off = 0;
    #pragma unroll
    for (int w = 0; w < 3; ++w) if (w < wid) off += wtot[w];
    cs[tid] = v + off;
    __syncthreads();

    const int total = cs[T_ - 1];
    const int mel   = min(total, max_len_p[0]);
    if (chunk == 0 && tid == 0) mel_out[b] = (float)mel;

    // --- threads 0..63: searchsorted(csum, pos, 'right') for this chunk ---
    if (tid < ROWS_PER_BLK) {
        const int pos = chunk * ROWS_PER_BLK + tid;
        int r = -1;
        if (pos < mel) {
            int lo = 0, hi = T_;                // first t with cs[t] > pos
            #pragma unroll
            for (int s = 0; s < 8; ++s) {
                int mid = (lo + hi) >> 1;
                if (cs[mid] <= pos) lo = mid + 1; else hi = mid;
            }
            r = min(lo, T_ - 1);
        }
        ridx[tid] = r;
    }
    __syncthreads();

    // --- gather + write: 64 rows x 96 f4 = 6144, 24 per thread, coalesced.
    // unroll 8 -> 8 outstanding gather loads per thread to hide L2/L3 latency.
    const int rowsz = D_ / 4;                                   // 96
    const f4* xb = x4 + (size_t)b * T_ * rowsz;
    f4* ob = out4 + ((size_t)b * ML_ + (size_t)chunk * ROWS_PER_BLK) * rowsz;
    const int N = ROWS_PER_BLK * rowsz;                         // 6144

    #pragma unroll 8
    for (int i = tid; i < N; i += 256) {
        const int rl  = i / rowsz;              // magic-mul div (rowsz const)
        const int ln  = i - rl * rowsz;
        const int idx = ridx[rl];
        f4 w;
        if (idx >= 0) w = xb[idx * rowsz + ln];
        else          w = (f4){0.f, 0.f, 0.f, 0.f};
        ob[i] = w;
    }
}

extern "C" void kernel_launch(void* const* d_in, const int* in_sizes, int n_in,
                              void* d_out, int out_size, void* d_ws, size_t ws_size,
                              hipStream_t stream) {
    const float* x       = (const float*)d_in[0];
    const int*   dur     = (const int*)d_in[1];
    const int*   max_len = (const int*)d_in[2];
    float*       out     = (float*)d_out;
    float*       mel_out = out + (size_t)B_ * ML_ * D_;         // tail: B_ floats

    lr_fused_kernel<<<B_ * CHUNKS, 256, 0, stream>>>(
        (const f4*)x, dur, max_len, (f4*)out, mel_out);
}